// Round 5
// baseline (75.823 us; speedup 1.0000x reference)
//
#include <hip/hip_runtime.h>
#include <hip/hip_bf16.h>

#define LN 262144
#define LMASK 262143
#define NCH 64
#define INV_L (1.0f/262144.0f)
#define BSTR 38    // fwd LDS stride (halfs): write<=2-way, read<=2-way banks
#define ISTR 138   // inv Bs stride (halfs): reads <=3-way
#define XSTR 66    // inv xpose stride (floats): ~conflict-free both sides

typedef short short8 __attribute__((ext_vector_type(8)));
typedef float f32x4 __attribute__((ext_vector_type(4)));

static __device__ __forceinline__ unsigned short f2bf(float x) {
    union { __hip_bfloat16 b; unsigned short u; } cv;
    cv.b = __float2bfloat16(x);   // RNE; compiler may pack via v_cvt_pk_bf16_f32
    return cv.u;
}
static __device__ __forceinline__ float fsin01(float rev) {  // sin(2*pi*rev)
    float r; asm("v_sin_f32 %0, %1" : "=v"(r) : "v"(rev)); return r;
}
static __device__ __forceinline__ float fcos01(float rev) {  // cos(2*pi*rev)
    float r; asm("v_cos_f32 %0, %1" : "=v"(r) : "v"(rev)); return r;
}

// ---------------- K1: forward DFT partials via MFMA ----------------
// grid: nb x 256 (4 waves). Wave w owns modes 16w..16w+15.
// Double-buffered LDS, 3-deep tile pipeline, 1 barrier per 32-row K-step.
__global__ __launch_bounds__(256) void fno_fwd(const float* __restrict__ u,
                                               float* __restrict__ part, int nb) {
    __shared__ __align__(16) unsigned short Bt[2][64 * BSTR];
    const int tid = threadIdx.x;
    const int lane = tid & 63;
    const int w = tid >> 6;
    const int chunk = LN / nb;
    const int ksteps = chunk >> 5;
    const int n0 = blockIdx.x * chunk;

    const int kkst = tid >> 3;   // staging row 0..31
    const int gst = tid & 7;     // staging channel group

    const int l15 = lane & 15;
    const int hk = lane >> 4;
    const int m = w * 16 + l15;  // this lane's mode

    // rotation state for kk = hk*8 + j, advanced 32 rows per step
    float cR[8], sR[8];
    #pragma unroll
    for (int j = 0; j < 8; ++j) {
        int ph = (m * (n0 + hk * 8 + j)) & LMASK;
        cR[j] = fcos01((float)ph * INV_L);
        sR[j] = fsin01((float)ph * INV_L);
    }
    float cD, sD;
    {
        int ph = (m * 32) & LMASK;
        cD = fcos01((float)ph * INV_L);
        sD = fsin01((float)ph * INV_L);
    }

    f32x4 accC[4], accS[4];
    #pragma unroll
    for (int t = 0; t < 4; ++t) { accC[t] = (f32x4){0,0,0,0}; accS[t] = (f32x4){0,0,0,0}; }

    const float* __restrict__ ub = u + (size_t)(n0 + kkst) * NCH + gst * 8;
    const size_t tstep = 32 * NCH;

    // pipeline: regA = tile to stage next, regB = tile behind it
    float4 a0 = *(const float4*)(ub);
    float4 a1 = *(const float4*)(ub + 4);
    float4 b0 = *(const float4*)(ub + tstep);
    float4 b1 = *(const float4*)(ub + tstep + 4);
    {   // stage tile 0 -> buf 0
        float uv[8] = {a0.x, a0.y, a0.z, a0.w, a1.x, a1.y, a1.z, a1.w};
        #pragma unroll
        for (int q = 0; q < 8; ++q)
            Bt[0][(gst * 8 + q) * BSTR + kkst] = f2bf(uv[q]);
    }
    a0 = b0; a1 = b1;
    b0 = *(const float4*)(ub + 2 * tstep);
    b1 = *(const float4*)(ub + 2 * tstep + 4);

    for (int t = 0; t < ksteps; ++t) {
        __syncthreads();
        if (t + 1 < ksteps) {   // stage tile t+1 (regA) into other buffer
            float uv[8] = {a0.x, a0.y, a0.z, a0.w, a1.x, a1.y, a1.z, a1.w};
            unsigned short* bt = Bt[(t + 1) & 1];
            #pragma unroll
            for (int q = 0; q < 8; ++q)
                bt[(gst * 8 + q) * BSTR + kkst] = f2bf(uv[q]);
        }
        a0 = b0; a1 = b1;
        if (t + 3 < ksteps) {   // prefetch tile t+3
            const float* pn = ub + (size_t)(t + 3) * tstep;
            b0 = *(const float4*)(pn);
            b1 = *(const float4*)(pn + 4);
        }
        // A fragments from rotation state
        short8 aC, aS;
        #pragma unroll
        for (int j = 0; j < 8; ++j) {
            aC[j] = (short)f2bf(cR[j]);
            aS[j] = (short)f2bf(-sR[j]);
        }
        #pragma unroll
        for (int j = 0; j < 8; ++j) {
            float c2 = cR[j] * cD - sR[j] * sD;
            sR[j] = fmaf(sR[j], cD, cR[j] * sD);
            cR[j] = c2;
        }
        const unsigned short* bt = Bt[t & 1];
        #pragma unroll
        for (int tn = 0; tn < 4; ++tn) {
            const short8 bf = *(const short8*)&bt[(tn * 16 + l15) * BSTR + hk * 8];
            accC[tn] = __builtin_amdgcn_mfma_f32_16x16x32_bf16(aC, bf, accC[tn], 0, 0, 0);
            accS[tn] = __builtin_amdgcn_mfma_f32_16x16x32_bf16(aS, bf, accS[tn], 0, 0, 0);
        }
    }
    // C/D: col=lane&15, row=(lane>>4)*4+reg
    float* baseR = part + (size_t)blockIdx.x * 8192;
    #pragma unroll
    for (int tn = 0; tn < 4; ++tn) {
        #pragma unroll
        for (int r = 0; r < 4; ++r) {
            int k = w * 16 + hk * 4 + r;
            int i = tn * 16 + l15;
            baseR[k * 64 + i] = accC[tn][r];
            baseR[4096 + k * 64 + i] = accS[tn][r];
        }
    }
}

// ---------------- K2a: reduce partials (coalesced) + z_local ----------------
// blocks 0..63: uhat[g] = sum_b part[b*8192+g] for 128 g's each.
// block 64: z_local -> coef[8192..8255].
__global__ __launch_bounds__(256) void fno_red(const float* __restrict__ part, int nb,
                                               const float* __restrict__ W,
                                               const float* __restrict__ u,
                                               const float* __restrict__ y,
                                               float* __restrict__ uhat,
                                               float* __restrict__ coef) {
    const int tid = threadIdx.x;
    if (blockIdx.x == 64) {
        if (tid < 64) {
            const int idx = (int)(y[0] * (float)LN);
            float zl = 0.f;
            #pragma unroll 8
            for (int ii = 0; ii < 64; ++ii)
                zl = fmaf(W[tid * 64 + ii], u[(size_t)idx * 64 + ii], zl);
            coef[8192 + tid] = zl;
        }
        return;
    }
    const int g = blockIdx.x * 128 + (tid & 127);
    const int h = tid >> 7;  // 0..1
    float s = 0.f;
    #pragma unroll 8
    for (int b = h; b < nb; b += 2)
        s += part[(size_t)b * 8192 + g];
    __shared__ float sh[2][128];
    sh[h][tid & 127] = s;
    __syncthreads();
    if (h == 0) uhat[g] = sh[0][tid] + sh[1][tid];
}

// ---------------- K2b: apply Kc -> coefficients (lane = mode, coalesced Kt) ----------------
// grid: 8 blocks x 512. wave -> one output channel o; lane -> mode m.
// coef[0..4095]=A(cos), coef[4096..8191]=B(sin)
__global__ __launch_bounds__(512) void fno_coef(const float* __restrict__ uhat,
                                                const float* __restrict__ Kt,
                                                float* __restrict__ coef) {
    __shared__ float ure[64 * 65], uim[64 * 65];
    const int tid = threadIdx.x;
    for (int e = tid; e < 4096; e += 512) {
        int k = e >> 6, ii = e & 63;
        ure[ii * 65 + k] = uhat[e];
        uim[ii * 65 + k] = uhat[4096 + e];
    }
    __syncthreads();
    const int m = tid & 63;
    const int o = blockIdx.x * 8 + (tid >> 6);
    const float* __restrict__ K0 = Kt + (size_t)o * 64 + m;  // + ii*4096
    const float* __restrict__ K1 = K0 + 262144;
    float zr = 0.f, zi = 0.f;
    #pragma unroll 8
    for (int ii = 0; ii < 64; ++ii) {
        float k0 = K0[(size_t)ii * 4096];
        float k1 = K1[(size_t)ii * 4096];
        float re = ure[ii * 65 + m];
        float im = uim[ii * 65 + m];
        zr = fmaf(re, k0, fmaf(-im, k1, zr));
        zi = fmaf(re, k1, fmaf(im, k0, zi));
    }
    if (m == 0) {
        coef[o] = zr * INV_L;          // DC: only Re enters irfft
        coef[4096 + o] = 0.f;
    } else {
        coef[m * 64 + o] = 2.f * zr * INV_L;
        coef[4096 + m * 64 + o] = -2.f * zi * INV_L;
    }
}

// ---------------- K3: inverse via MFMA ----------------
// Trig A-matrix: per (p,half): 1 sincos + 7 complex rotations (cos AND sin
// tiles share the same phase grid). Linear 1KB stores via per-wave xpose.
__global__ __launch_bounds__(256) void fno_inv(const float* __restrict__ coef,
                                               float* __restrict__ out) {
    __shared__ __align__(16) unsigned short Bs[64 * ISTR];  // [ch][cos 0..63 | sin 0..63]
    __shared__ float zloc[64];
    __shared__ float xpose[4][16 * XSTR];
    const int tid = threadIdx.x;
    const int lane = tid & 63;
    const int w = tid >> 6;

    for (int e = tid; e < 4096; e += 256) {
        int mm = e >> 6, ch = e & 63;
        Bs[ch * ISTR + mm] = f2bf(coef[e]);
        Bs[ch * ISTR + 64 + mm] = f2bf(coef[4096 + e]);
    }
    if (tid < 64) zloc[tid] = coef[8192 + tid];
    __syncthreads();

    const int l15 = lane & 15;
    const int hk = lane >> 4;
    const int rl = lane >> 4;        // store: local row quarter
    const int cq = lane & 15;        // store: channel quarter (4 ch)
    float4 zv = *(const float4*)&zloc[cq * 4];

    for (int p = 0; p < 4; ++p) {
        const int nbase = blockIdx.x * 256 + (p * 4 + w) * 16;
        const int row = nbase + l15;
        float cstp = fcos01((float)row * INV_L);
        float sstp = fsin01((float)row * INV_L);

        short8 aF[4];
        #pragma unroll
        for (int h = 0; h < 2; ++h) {
            const int m0 = h * 32 + hk * 8;
            const int ph = (row * m0) & LMASK;
            float c = fcos01((float)ph * INV_L);
            float s = fsin01((float)ph * INV_L);
            #pragma unroll
            for (int jj = 0; jj < 8; ++jj) {
                aF[h][jj] = (short)f2bf(c);
                aF[2 + h][jj] = (short)f2bf(s);
                float c2 = c * cstp - s * sstp;
                s = fmaf(s, cstp, c * sstp);
                c = c2;
            }
        }

        f32x4 acc[4];
        #pragma unroll
        for (int tn = 0; tn < 4; ++tn) acc[tn] = (f32x4){0,0,0,0};
        #pragma unroll
        for (int ks = 0; ks < 4; ++ks) {
            #pragma unroll
            for (int tn = 0; tn < 4; ++tn) {
                const short8 bf = *(const short8*)&Bs[(tn * 16 + l15) * ISTR + ks * 32 + hk * 8];
                acc[tn] = __builtin_amdgcn_mfma_f32_16x16x32_bf16(aF[ks], bf, acc[tn], 0, 0, 0);
            }
        }
        // per-wave transpose -> fully linear stores (1KB per instruction)
        #pragma unroll
        for (int tn = 0; tn < 4; ++tn)
            #pragma unroll
            for (int r = 0; r < 4; ++r)
                xpose[w][(hk * 4 + r) * XSTR + tn * 16 + l15] = acc[tn][r];
        __builtin_amdgcn_s_waitcnt(0);  // wave-local LDS ordering
        #pragma unroll
        for (int rg = 0; rg < 4; ++rg) {
            const int rowl = rg * 4 + rl;
            float4 v = *(const float4*)&xpose[w][rowl * XSTR + cq * 4];
            v.x += zv.x; v.y += zv.y; v.z += zv.z; v.w += zv.w;
            *(float4*)(out + (size_t)(nbase + rowl) * NCH + cq * 4) = v;
        }
    }
}

extern "C" void kernel_launch(void* const* d_in, const int* in_sizes, int n_in,
                              void* d_out, int out_size, void* d_ws, size_t ws_size,
                              hipStream_t stream) {
    const float* u = (const float*)d_in[0];
    const float* y = (const float*)d_in[1];
    const float* K = (const float*)d_in[2];
    const float* W = (const float*)d_in[3];
    float* out = (float*)d_out;
    float* ws = (float*)d_ws;

    int nb = 1024;
    while (nb > 64 && ((size_t)(nb * 8192 + 8192 + 8256) * 4) > ws_size) nb >>= 1;

    float* part = ws;                       // nb*8192
    float* uhat = ws + (size_t)nb * 8192;   // 8192
    float* coef = uhat + 8192;              // 8192 + 64

    fno_fwd<<<nb, 256, 0, stream>>>(u, part, nb);
    fno_red<<<65, 256, 0, stream>>>(part, nb, W, u, y, uhat, coef);
    fno_coef<<<8, 512, 0, stream>>>(uhat, K, coef);
    fno_inv<<<1024, 256, 0, stream>>>(coef, out);
}

// Round 6
// 71.147 us; speedup vs baseline: 1.0657x; 1.0657x over previous
//
#include <hip/hip_runtime.h>

#define LN 262144
#define LMASK 262143
#define NCH 64
#define INV_L (1.0f/262144.0f)
#define BSTR 38    // fwd LDS stride (halfs): write<=2-way, read<=2-way banks
#define ISTR 138   // inv Bs stride (halfs): reads <=2-way
#define XSTR 66    // inv xpose stride (floats): ~conflict-free both sides

typedef short short8 __attribute__((ext_vector_type(8)));
typedef float f32x4 __attribute__((ext_vector_type(4)));

static __device__ __forceinline__ unsigned short f2bf(float x) {
    union { float f; unsigned u; } v; v.f = x;
    unsigned r = (v.u + 0x7fff + ((v.u >> 16) & 1)) >> 16;
    return (unsigned short)r;
}
static __device__ __forceinline__ float bf2f(unsigned short b) {
    union { unsigned u; float f; } v; v.u = ((unsigned)b) << 16;
    return v.f;
}
static __device__ __forceinline__ float fsin01(float rev) {  // sin(2*pi*rev)
    float r; asm("v_sin_f32 %0, %1" : "=v"(r) : "v"(rev)); return r;
}
static __device__ __forceinline__ float fcos01(float rev) {  // cos(2*pi*rev)
    float r; asm("v_cos_f32 %0, %1" : "=v"(r) : "v"(rev)); return r;
}

// ---------------- K1: forward DFT partials via MFMA ----------------
// grid: nb x 256 (4 waves). Wave w owns modes 16w..16w+15.
// Double-buffered LDS, 3-deep tile pipeline, 1 barrier per 32-row K-step.
// Partials stored bf16 (spectral branch has ~500x error headroom).
__global__ __launch_bounds__(256) void fno_fwd(const float* __restrict__ u,
                                               unsigned short* __restrict__ part, int nb) {
    __shared__ __align__(16) unsigned short Bt[2][64 * BSTR];
    const int tid = threadIdx.x;
    const int lane = tid & 63;
    const int w = tid >> 6;
    const int chunk = LN / nb;
    const int ksteps = chunk >> 5;
    const int n0 = blockIdx.x * chunk;

    const int kkst = tid >> 3;   // staging row 0..31
    const int gst = tid & 7;     // staging channel group

    const int l15 = lane & 15;
    const int hk = lane >> 4;
    const int m = w * 16 + l15;  // this lane's mode

    // rotation state for kk = hk*8 + j, advanced 32 rows per step
    float cR[8], sR[8];
    #pragma unroll
    for (int j = 0; j < 8; ++j) {
        int ph = (m * (n0 + hk * 8 + j)) & LMASK;
        cR[j] = fcos01((float)ph * INV_L);
        sR[j] = fsin01((float)ph * INV_L);
    }
    float cD, sD;
    {
        int ph = (m * 32) & LMASK;
        cD = fcos01((float)ph * INV_L);
        sD = fsin01((float)ph * INV_L);
    }

    f32x4 accC[4], accS[4];
    #pragma unroll
    for (int t = 0; t < 4; ++t) { accC[t] = (f32x4){0,0,0,0}; accS[t] = (f32x4){0,0,0,0}; }

    const float* __restrict__ ub = u + (size_t)(n0 + kkst) * NCH + gst * 8;
    const size_t tstep = 32 * NCH;

    // pipeline: regA = tile to stage next, regB = tile behind it
    float4 a0 = *(const float4*)(ub);
    float4 a1 = *(const float4*)(ub + 4);
    float4 b0 = *(const float4*)(ub + tstep);
    float4 b1 = *(const float4*)(ub + tstep + 4);
    {   // stage tile 0 -> buf 0
        float uv[8] = {a0.x, a0.y, a0.z, a0.w, a1.x, a1.y, a1.z, a1.w};
        #pragma unroll
        for (int q = 0; q < 8; ++q)
            Bt[0][(gst * 8 + q) * BSTR + kkst] = f2bf(uv[q]);
    }
    a0 = b0; a1 = b1;
    b0 = *(const float4*)(ub + 2 * tstep);
    b1 = *(const float4*)(ub + 2 * tstep + 4);

    for (int t = 0; t < ksteps; ++t) {
        __syncthreads();
        if (t + 1 < ksteps) {   // stage tile t+1 (regA) into other buffer
            float uv[8] = {a0.x, a0.y, a0.z, a0.w, a1.x, a1.y, a1.z, a1.w};
            unsigned short* bt = Bt[(t + 1) & 1];
            #pragma unroll
            for (int q = 0; q < 8; ++q)
                bt[(gst * 8 + q) * BSTR + kkst] = f2bf(uv[q]);
        }
        a0 = b0; a1 = b1;
        if (t + 3 < ksteps) {   // prefetch tile t+3
            const float* pn = ub + (size_t)(t + 3) * tstep;
            b0 = *(const float4*)(pn);
            b1 = *(const float4*)(pn + 4);
        }
        // A fragments from rotation state
        short8 aC, aS;
        #pragma unroll
        for (int j = 0; j < 8; ++j) {
            aC[j] = (short)f2bf(cR[j]);
            aS[j] = (short)f2bf(-sR[j]);
        }
        #pragma unroll
        for (int j = 0; j < 8; ++j) {
            float c2 = cR[j] * cD - sR[j] * sD;
            sR[j] = fmaf(sR[j], cD, cR[j] * sD);
            cR[j] = c2;
        }
        const unsigned short* bt = Bt[t & 1];
        #pragma unroll
        for (int tn = 0; tn < 4; ++tn) {
            const short8 bf = *(const short8*)&bt[(tn * 16 + l15) * BSTR + hk * 8];
            accC[tn] = __builtin_amdgcn_mfma_f32_16x16x32_bf16(aC, bf, accC[tn], 0, 0, 0);
            accS[tn] = __builtin_amdgcn_mfma_f32_16x16x32_bf16(aS, bf, accS[tn], 0, 0, 0);
        }
    }
    // C/D: col=lane&15, row=(lane>>4)*4+reg
    unsigned short* baseR = part + (size_t)blockIdx.x * 8192;
    #pragma unroll
    for (int tn = 0; tn < 4; ++tn) {
        #pragma unroll
        for (int r = 0; r < 4; ++r) {
            int k = w * 16 + hk * 4 + r;
            int i = tn * 16 + l15;
            baseR[k * 64 + i] = f2bf(accC[tn][r]);
            baseR[4096 + k * 64 + i] = f2bf(accS[tn][r]);
        }
    }
}

// ---------------- K2: reduce partials + apply Kc + z_local ----------------
// grid: 64 blocks (mode k) x 512 threads.
// coef[0..4095]=A(cos), coef[4096..8191]=B(sin), coef[8192..8255]=z_local
__global__ __launch_bounds__(512) void fno_redcoef(const unsigned short* __restrict__ part, int nb,
                                                   const float* __restrict__ Kt,
                                                   const float* __restrict__ W,
                                                   const float* __restrict__ u,
                                                   const float* __restrict__ y,
                                                   float* __restrict__ coef) {
    const int k = blockIdx.x;
    const int t = threadIdx.x;
    const int j = t & 127;
    const int h = t >> 7;  // 0..3

    const unsigned short* __restrict__ pb =
        part + (size_t)k * 64 + (j & 63) + ((j >> 6) ? 4096 : 0);
    float s = 0.f;
    #pragma unroll 8
    for (int b = h; b < nb; b += 4)
        s += bf2f(pb[(size_t)b * 8192]);

    __shared__ float red[4][128];
    __shared__ float uh[128];
    red[h][j] = s;
    __syncthreads();
    if (t < 128) uh[t] = red[0][t] + red[1][t] + red[2][t] + red[3][t];
    __syncthreads();

    if (t < 64) {
        const int o = t;
        float zr = 0.f, zi = 0.f;
        #pragma unroll 8
        for (int ii = 0; ii < 64; ++ii) {
            float k0v = Kt[(size_t)(ii * 64 + o) * 64 + k];
            float k1v = Kt[262144 + (size_t)(ii * 64 + o) * 64 + k];
            zr = fmaf(uh[ii], k0v, fmaf(-uh[64 + ii], k1v, zr));
            zi = fmaf(uh[ii], k1v, fmaf(uh[64 + ii], k0v, zi));
        }
        if (k == 0) {
            const int idx = (int)(y[0] * (float)LN);
            float zl = 0.f;
            for (int ii = 0; ii < 64; ++ii)
                zl = fmaf(W[o * 64 + ii], u[(size_t)idx * 64 + ii], zl);
            coef[o] = zr * INV_L;
            coef[4096 + o] = 0.f;
            coef[8192 + o] = zl;
        } else {
            coef[k * 64 + o] = 2.f * zr * INV_L;
            coef[4096 + k * 64 + o] = -2.f * zi * INV_L;
        }
    }
}

// ---------------- K3: inverse via MFMA ----------------
// Trig A-matrix: per (p,half): 1 sincos + 7 complex rotations (cos AND sin
// tiles share the same phase grid). Linear 1KB stores via per-wave xpose.
__global__ __launch_bounds__(256) void fno_inv(const float* __restrict__ coef,
                                               float* __restrict__ out) {
    __shared__ __align__(16) unsigned short Bs[64 * ISTR];  // [ch][cos 0..63 | sin 0..63]
    __shared__ float zloc[64];
    __shared__ float xpose[4][16 * XSTR];
    const int tid = threadIdx.x;
    const int lane = tid & 63;
    const int w = tid >> 6;

    for (int e = tid; e < 4096; e += 256) {
        int mm = e >> 6, ch = e & 63;
        Bs[ch * ISTR + mm] = f2bf(coef[e]);
        Bs[ch * ISTR + 64 + mm] = f2bf(coef[4096 + e]);
    }
    if (tid < 64) zloc[tid] = coef[8192 + tid];
    __syncthreads();

    const int l15 = lane & 15;
    const int hk = lane >> 4;
    const int rl = lane >> 4;        // store: local row quarter
    const int cq = lane & 15;        // store: channel quarter (4 ch)
    float4 zv = *(const float4*)&zloc[cq * 4];

    for (int p = 0; p < 4; ++p) {
        const int nbase = blockIdx.x * 256 + (p * 4 + w) * 16;
        const int row = nbase + l15;
        float cstp = fcos01((float)row * INV_L);
        float sstp = fsin01((float)row * INV_L);

        short8 aF[4];
        #pragma unroll
        for (int h = 0; h < 2; ++h) {
            const int m0 = h * 32 + hk * 8;
            const int ph = (row * m0) & LMASK;
            float c = fcos01((float)ph * INV_L);
            float s = fsin01((float)ph * INV_L);
            #pragma unroll
            for (int jj = 0; jj < 8; ++jj) {
                aF[h][jj] = (short)f2bf(c);
                aF[2 + h][jj] = (short)f2bf(s);
                float c2 = c * cstp - s * sstp;
                s = fmaf(s, cstp, c * sstp);
                c = c2;
            }
        }

        f32x4 acc[4];
        #pragma unroll
        for (int tn = 0; tn < 4; ++tn) acc[tn] = (f32x4){0,0,0,0};
        #pragma unroll
        for (int ks = 0; ks < 4; ++ks) {
            #pragma unroll
            for (int tn = 0; tn < 4; ++tn) {
                const short8 bf = *(const short8*)&Bs[(tn * 16 + l15) * ISTR + ks * 32 + hk * 8];
                acc[tn] = __builtin_amdgcn_mfma_f32_16x16x32_bf16(aF[ks], bf, acc[tn], 0, 0, 0);
            }
        }
        // per-wave transpose -> fully linear stores (1KB per instruction)
        #pragma unroll
        for (int tn = 0; tn < 4; ++tn)
            #pragma unroll
            for (int r = 0; r < 4; ++r)
                xpose[w][(hk * 4 + r) * XSTR + tn * 16 + l15] = acc[tn][r];
        asm volatile("s_waitcnt lgkmcnt(0)" ::: "memory");  // LDS-only drain (NOT vmcnt)
        #pragma unroll
        for (int rg = 0; rg < 4; ++rg) {
            const int rowl = rg * 4 + rl;
            float4 v = *(const float4*)&xpose[w][rowl * XSTR + cq * 4];
            v.x += zv.x; v.y += zv.y; v.z += zv.z; v.w += zv.w;
            *(float4*)(out + (size_t)(nbase + rowl) * NCH + cq * 4) = v;
        }
    }
}

extern "C" void kernel_launch(void* const* d_in, const int* in_sizes, int n_in,
                              void* d_out, int out_size, void* d_ws, size_t ws_size,
                              hipStream_t stream) {
    const float* u = (const float*)d_in[0];
    const float* y = (const float*)d_in[1];
    const float* K = (const float*)d_in[2];
    const float* W = (const float*)d_in[3];
    float* out = (float*)d_out;

    int nb = 1024;
    while (nb > 64 && ((size_t)nb * 8192 * 2 + (size_t)8256 * 4 + 64) > ws_size) nb >>= 1;

    unsigned short* part = (unsigned short*)d_ws;          // nb*8192 bf16
    float* coef = (float*)((char*)d_ws + ((size_t)nb * 8192 * 2 + 63) / 64 * 64); // 8192+64 f32

    fno_fwd<<<nb, 256, 0, stream>>>(u, part, nb);
    fno_redcoef<<<64, 512, 0, stream>>>(part, nb, K, W, u, y, coef);
    fno_inv<<<1024, 256, 0, stream>>>(coef, out);
}

// Round 7
// 60.005 us; speedup vs baseline: 1.2636x; 1.1857x over previous
//
#include <hip/hip_runtime.h>

#define LN 262144
#define LMASK 262143
#define NCH 64
#define INV_L (1.0f/262144.0f)
#define BSTR 38    // fwd LDS stride (halfs): write<=2-way, read<=2-way banks
#define ISTR 138   // inv Bs stride (halfs): reads <=2-way
#define XSTR 66    // inv xpose stride (floats): ~conflict-free both sides

typedef short short8 __attribute__((ext_vector_type(8)));
typedef float f32x4 __attribute__((ext_vector_type(4)));

union s8i4 { int4 i; short8 s; };

// pack two f32 -> two bf16 (truncation round) in ONE v_perm_b32
static __device__ __forceinline__ unsigned pkbf(float lo, float hi) {
    union { float f; unsigned u; } a, b; a.f = lo; b.f = hi;
    return __builtin_amdgcn_perm(b.u, a.u, 0x07060302u);
}
static __device__ __forceinline__ short8 pk8(const float* v) {
    s8i4 cv;
    cv.i = make_int4(pkbf(v[0], v[1]), pkbf(v[2], v[3]),
                     pkbf(v[4], v[5]), pkbf(v[6], v[7]));
    return cv.s;
}
static __device__ __forceinline__ unsigned short f2bf_t(float x) {  // truncate
    union { float f; unsigned u; } v; v.f = x;
    return (unsigned short)(v.u >> 16);
}
static __device__ __forceinline__ float fsin01(float rev) {  // sin(2*pi*rev)
    float r; asm("v_sin_f32 %0, %1" : "=v"(r) : "v"(rev)); return r;
}
static __device__ __forceinline__ float fcos01(float rev) {  // cos(2*pi*rev)
    float r; asm("v_cos_f32 %0, %1" : "=v"(r) : "v"(rev)); return r;
}

// ---------------- K1: forward DFT partials via MFMA ----------------
// grid: 512 x 256 (4 waves). Wave w owns modes 16w..16w+15.
// Double-buffered LDS, 3-deep tile pipeline, 1 barrier per 32-row K-step.
// Rotation state kept as (cos, -sin) so the sin-fragment needs no negation.
__global__ __launch_bounds__(256) void fno_fwd(const float* __restrict__ u,
                                               float* __restrict__ part, int nb) {
    __shared__ __align__(16) unsigned short Bt[2][64 * BSTR];
    const int tid = threadIdx.x;
    const int lane = tid & 63;
    const int w = tid >> 6;
    const int chunk = LN / nb;
    const int ksteps = chunk >> 5;
    const int n0 = blockIdx.x * chunk;

    const int kkst = tid >> 3;   // staging row 0..31
    const int gst = tid & 7;     // staging channel group

    const int l15 = lane & 15;
    const int hk = lane >> 4;
    const int m = w * 16 + l15;  // this lane's mode

    // rotation state (c, ns=-sin) for kk = hk*8 + j, advanced 32 rows per step
    float cR[8], nsR[8];
    #pragma unroll
    for (int j = 0; j < 8; ++j) {
        int ph = (m * (n0 + hk * 8 + j)) & LMASK;
        cR[j] = fcos01((float)ph * INV_L);
        nsR[j] = -fsin01((float)ph * INV_L);
    }
    float cD, sD;
    {
        int ph = (m * 32) & LMASK;
        cD = fcos01((float)ph * INV_L);
        sD = fsin01((float)ph * INV_L);
    }

    f32x4 accC[4], accS[4];
    #pragma unroll
    for (int t = 0; t < 4; ++t) { accC[t] = (f32x4){0,0,0,0}; accS[t] = (f32x4){0,0,0,0}; }

    const float* __restrict__ ub = u + (size_t)(n0 + kkst) * NCH + gst * 8;
    const size_t tstep = 32 * NCH;

    // pipeline: regA = tile to stage next, regB = tile behind it
    float4 a0 = *(const float4*)(ub);
    float4 a1 = *(const float4*)(ub + 4);
    float4 b0 = *(const float4*)(ub + tstep);
    float4 b1 = *(const float4*)(ub + tstep + 4);
    {   // stage tile 0 -> buf 0
        float uv[8] = {a0.x, a0.y, a0.z, a0.w, a1.x, a1.y, a1.z, a1.w};
        #pragma unroll
        for (int q = 0; q < 8; ++q)
            Bt[0][(gst * 8 + q) * BSTR + kkst] = f2bf_t(uv[q]);
    }
    a0 = b0; a1 = b1;
    b0 = *(const float4*)(ub + 2 * tstep);
    b1 = *(const float4*)(ub + 2 * tstep + 4);

    for (int t = 0; t < ksteps; ++t) {
        __syncthreads();
        if (t + 1 < ksteps) {   // stage tile t+1 (regA) into other buffer
            float uv[8] = {a0.x, a0.y, a0.z, a0.w, a1.x, a1.y, a1.z, a1.w};
            unsigned short* bt = Bt[(t + 1) & 1];
            #pragma unroll
            for (int q = 0; q < 8; ++q)
                bt[(gst * 8 + q) * BSTR + kkst] = f2bf_t(uv[q]);
        }
        a0 = b0; a1 = b1;
        if (t + 3 < ksteps) {   // prefetch tile t+3
            const float* pn = ub + (size_t)(t + 3) * tstep;
            b0 = *(const float4*)(pn);
            b1 = *(const float4*)(pn + 4);
        }
        // A fragments: 8 v_perm packs total
        const short8 aC = pk8(cR);
        const short8 aS = pk8(nsR);
        #pragma unroll
        for (int j = 0; j < 8; ++j) {   // advance rotation by 32 rows
            float c2 = cR[j] * cD + nsR[j] * sD;
            nsR[j] = nsR[j] * cD - cR[j] * sD;
            cR[j] = c2;
        }
        const unsigned short* bt = Bt[t & 1];
        #pragma unroll
        for (int tn = 0; tn < 4; ++tn) {
            const short8 bf = *(const short8*)&bt[(tn * 16 + l15) * BSTR + hk * 8];
            accC[tn] = __builtin_amdgcn_mfma_f32_16x16x32_bf16(aC, bf, accC[tn], 0, 0, 0);
            accS[tn] = __builtin_amdgcn_mfma_f32_16x16x32_bf16(aS, bf, accS[tn], 0, 0, 0);
        }
    }
    // C/D: col=lane&15, row=(lane>>4)*4+reg
    float* baseR = part + (size_t)blockIdx.x * 8192;
    #pragma unroll
    for (int tn = 0; tn < 4; ++tn) {
        #pragma unroll
        for (int r = 0; r < 4; ++r) {
            int k = w * 16 + hk * 4 + r;
            int i = tn * 16 + l15;
            baseR[k * 64 + i] = accC[tn][r];
            baseR[4096 + k * 64 + i] = accS[tn][r];
        }
    }
}

// ---------------- K2: reduce partials (float4) + apply Kc + z_local ----------------
// grid: 64 blocks (mode k) x 512 threads.
// coef[0..4095]=A(cos), coef[4096..8191]=B(sin), coef[8192..8255]=z_local
__global__ __launch_bounds__(512) void fno_redcoef(const float* __restrict__ part, int nb,
                                                   const float* __restrict__ Kt,
                                                   const float* __restrict__ W,
                                                   const float* __restrict__ u,
                                                   const float* __restrict__ y,
                                                   float* __restrict__ coef) {
    const int k = blockIdx.x;
    const int t = threadIdx.x;
    const int j = t & 31;   // 0..15: re quad j, 16..31: im quad j-16
    const int h = t >> 5;   // 0..15 (b-interleave)

    const float* __restrict__ pb =
        part + (size_t)k * 64 + (j & 15) * 4 + ((j >> 4) ? 4096 : 0);
    float4 s4 = make_float4(0.f, 0.f, 0.f, 0.f);
    #pragma unroll 4
    for (int b = h; b < nb; b += 16) {
        float4 v = *(const float4*)&pb[(size_t)b * 8192];
        s4.x += v.x; s4.y += v.y; s4.z += v.z; s4.w += v.w;
    }
    __shared__ float4 red4[16][32];
    __shared__ float uh[128];
    red4[h][j] = s4;
    __syncthreads();
    if (t < 32) {
        float4 acc = red4[0][t];
        #pragma unroll
        for (int hh = 1; hh < 16; ++hh) {
            float4 v = red4[hh][t];
            acc.x += v.x; acc.y += v.y; acc.z += v.z; acc.w += v.w;
        }
        const int base = (t >> 4) * 64 + (t & 15) * 4;
        uh[base + 0] = acc.x; uh[base + 1] = acc.y;
        uh[base + 2] = acc.z; uh[base + 3] = acc.w;
    }
    __syncthreads();

    if (t < 64) {
        const int o = t;
        float zr = 0.f, zi = 0.f;
        #pragma unroll 8
        for (int ii = 0; ii < 64; ++ii) {
            float k0v = Kt[(size_t)(ii * 64 + o) * 64 + k];
            float k1v = Kt[262144 + (size_t)(ii * 64 + o) * 64 + k];
            zr = fmaf(uh[ii], k0v, fmaf(-uh[64 + ii], k1v, zr));
            zi = fmaf(uh[ii], k1v, fmaf(uh[64 + ii], k0v, zi));
        }
        if (k == 0) {
            const int idx = (int)(y[0] * (float)LN);
            float zl = 0.f;
            for (int ii = 0; ii < 64; ++ii)
                zl = fmaf(W[o * 64 + ii], u[(size_t)idx * 64 + ii], zl);
            coef[o] = zr * INV_L;
            coef[4096 + o] = 0.f;
            coef[8192 + o] = zl;
        } else {
            coef[k * 64 + o] = 2.f * zr * INV_L;
            coef[4096 + k * 64 + o] = -2.f * zi * INV_L;
        }
    }
}

// ---------------- K3: inverse via MFMA ----------------
// Trig A-matrix: per (p,half): 1 sincos + 7 complex rotations, v_perm packing.
// Linear 1KB stores via per-wave xpose.
__global__ __launch_bounds__(256) void fno_inv(const float* __restrict__ coef,
                                               float* __restrict__ out) {
    __shared__ __align__(16) unsigned short Bs[64 * ISTR];  // [ch][cos 0..63 | sin 0..63]
    __shared__ float zloc[64];
    __shared__ float xpose[4][16 * XSTR];
    const int tid = threadIdx.x;
    const int lane = tid & 63;
    const int w = tid >> 6;

    for (int e = tid; e < 4096; e += 256) {
        int mm = e >> 6, ch = e & 63;
        Bs[ch * ISTR + mm] = f2bf_t(coef[e]);
        Bs[ch * ISTR + 64 + mm] = f2bf_t(coef[4096 + e]);
    }
    if (tid < 64) zloc[tid] = coef[8192 + tid];
    __syncthreads();

    const int l15 = lane & 15;
    const int hk = lane >> 4;
    const int rl = lane >> 4;        // store: local row quarter
    const int cq = lane & 15;        // store: channel quarter (4 ch)
    float4 zv = *(const float4*)&zloc[cq * 4];

    for (int p = 0; p < 4; ++p) {
        const int nbase = blockIdx.x * 256 + (p * 4 + w) * 16;
        const int row = nbase + l15;
        float cstp = fcos01((float)row * INV_L);
        float sstp = fsin01((float)row * INV_L);

        short8 aF[4];
        #pragma unroll
        for (int h = 0; h < 2; ++h) {
            const int m0 = h * 32 + hk * 8;
            const int ph = (row * m0) & LMASK;
            float c = fcos01((float)ph * INV_L);
            float s = fsin01((float)ph * INV_L);
            float cv[8], sv[8];
            #pragma unroll
            for (int jj = 0; jj < 8; ++jj) {
                cv[jj] = c; sv[jj] = s;
                float c2 = c * cstp - s * sstp;
                s = fmaf(s, cstp, c * sstp);
                c = c2;
            }
            aF[h] = pk8(cv);
            aF[2 + h] = pk8(sv);
        }

        f32x4 acc[4];
        #pragma unroll
        for (int tn = 0; tn < 4; ++tn) acc[tn] = (f32x4){0,0,0,0};
        #pragma unroll
        for (int ks = 0; ks < 4; ++ks) {
            #pragma unroll
            for (int tn = 0; tn < 4; ++tn) {
                const short8 bf = *(const short8*)&Bs[(tn * 16 + l15) * ISTR + ks * 32 + hk * 8];
                acc[tn] = __builtin_amdgcn_mfma_f32_16x16x32_bf16(aF[ks], bf, acc[tn], 0, 0, 0);
            }
        }
        // per-wave transpose -> fully linear stores (1KB per instruction)
        #pragma unroll
        for (int tn = 0; tn < 4; ++tn)
            #pragma unroll
            for (int r = 0; r < 4; ++r)
                xpose[w][(hk * 4 + r) * XSTR + tn * 16 + l15] = acc[tn][r];
        asm volatile("s_waitcnt lgkmcnt(0)" ::: "memory");  // LDS-only drain (NOT vmcnt)
        #pragma unroll
        for (int rg = 0; rg < 4; ++rg) {
            const int rowl = rg * 4 + rl;
            float4 v = *(const float4*)&xpose[w][rowl * XSTR + cq * 4];
            v.x += zv.x; v.y += zv.y; v.z += zv.z; v.w += zv.w;
            *(float4*)(out + (size_t)(nbase + rowl) * NCH + cq * 4) = v;
        }
    }
}

extern "C" void kernel_launch(void* const* d_in, const int* in_sizes, int n_in,
                              void* d_out, int out_size, void* d_ws, size_t ws_size,
                              hipStream_t stream) {
    const float* u = (const float*)d_in[0];
    const float* y = (const float*)d_in[1];
    const float* K = (const float*)d_in[2];
    const float* W = (const float*)d_in[3];
    float* out = (float*)d_out;
    float* ws = (float*)d_ws;

    int nb = 512;
    while (nb > 64 && ((size_t)(nb * 8192 + 8256) * 4) > ws_size) nb >>= 1;

    float* part = ws;                       // nb*8192
    float* coef = ws + (size_t)nb * 8192;   // 8192 + 64

    fno_fwd<<<nb, 256, 0, stream>>>(u, part, nb);
    fno_redcoef<<<64, 512, 0, stream>>>(part, nb, K, W, u, y, coef);
    fno_inv<<<1024, 256, 0, stream>>>(coef, out);
}